// Round 6
// baseline (80.203 us; speedup 1.0000x reference)
//
#include <hip/hip_runtime.h>

#define N_RAY 131072
#define NS 128
#define BIG_DELTA 1e10f
#define EPS 1e-10f

// DPP move with explicit identity for invalid/masked lanes (bound_ctrl=false).
#define DPPF(OLD, V, CTRL, RM) \
  __int_as_float(__builtin_amdgcn_update_dpp(__float_as_int(OLD), __float_as_int(V), (CTRL), (RM), 0xf, false))

// DPP ctrl encodings (gfx9/CDNA): row_shr:N = 0x110+N, wave_shl:1 = 0x130,
// wave_shr:1 = 0x138, row_bcast:15 = 0x142, row_bcast:31 = 0x143.

// Inclusive multiply-scan over 64 lanes (identity = 1.0).
__device__ __forceinline__ float mul_scan_incl(float p) {
    p *= DPPF(1.0f, p, 0x111, 0xf);
    p *= DPPF(1.0f, p, 0x112, 0xf);
    p *= DPPF(1.0f, p, 0x114, 0xf);
    p *= DPPF(1.0f, p, 0x118, 0xf);
    p *= DPPF(1.0f, p, 0x142, 0xa);   // rows 1,3 += lane15/47
    p *= DPPF(1.0f, p, 0x143, 0xc);   // rows 2,3 += lane31
    return p;
}

// Sum over 64 lanes -> uniform scalar (scan pattern, total lands in lane 63).
__device__ __forceinline__ float wave_sum(float v) {
    v += DPPF(0.0f, v, 0x111, 0xf);
    v += DPPF(0.0f, v, 0x112, 0xf);
    v += DPPF(0.0f, v, 0x114, 0xf);
    v += DPPF(0.0f, v, 0x118, 0xf);
    v += DPPF(0.0f, v, 0x142, 0xa);
    v += DPPF(0.0f, v, 0x143, 0xc);
    return __int_as_float(__builtin_amdgcn_readlane(__float_as_int(v), 63));
}

// One wave = 4 rays (sequential), 2 samples/lane, all loads staged up-front.
__global__ __launch_bounds__(256) void volrender_kernel(
    const float* __restrict__ rgb,
    const float* __restrict__ sigma,
    const float* __restrict__ z_vals,
    const int* __restrict__ wb_flag,
    float* __restrict__ out)
{
    const int lane = threadIdx.x & 63;
    const int wid  = (blockIdx.x * blockDim.x + threadIdx.x) >> 6;  // global wave
    const size_t ray0 = (size_t)wid * 4;

    // ---- stage all loads (max MLP; fully coalesced float2)
    float2 zv[4], sv[4], c01[4], c23[4], c45[4];
    #pragma unroll
    for (int k = 0; k < 4; ++k) {
        const size_t base = (ray0 + k) * NS + 2 * lane;
        zv[k] = *reinterpret_cast<const float2*>(&z_vals[base]);
        sv[k] = *reinterpret_cast<const float2*>(&sigma[base]);
        const float* rp = rgb + (ray0 + k) * (NS * 3) + 6 * lane;
        c01[k] = *reinterpret_cast<const float2*>(rp);
        c23[k] = *reinterpret_cast<const float2*>(rp + 2);
        c45[k] = *reinterpret_cast<const float2*>(rp + 4);
    }

    float crs[4], cgs[4], cbs[4], dps[4], ops[4];
    float* wout = out + (size_t)N_RAY * 5;

    #pragma unroll
    for (int k = 0; k < 4; ++k) {
        const float2 z = zv[k];
        const float2 s = sv[k];

        // z[2l+2] from lane l+1 (wave_shl:1); lane 63 overridden below
        float znext = DPPF(0.0f, z.x, 0x130, 0xf);
        float d0 = z.y - z.x;
        float d1 = (lane == 63) ? BIG_DELTA : (znext - z.y);

        float e0 = __expf(-d0 * fmaxf(s.x, 0.0f));
        float e1 = __expf(-d1 * fmaxf(s.y, 0.0f));
        float a0 = 1.0f - e0, a1 = 1.0f - e1;
        float t0 = e0 + EPS,  t1 = e1 + EPS;   // == 1 - alpha + EPS

        // exclusive cumprod across the wave
        float p = mul_scan_incl(t0 * t1);
        float E = DPPF(1.0f, p, 0x138, 0xf);   // wave_shr:1; lane0 = 1.0

        float w0 = a0 * E;
        float w1 = a1 * (E * t0);

        // weights out
        *reinterpret_cast<float2*>(&wout[(ray0 + k) * NS + 2 * lane]) =
            make_float2(w0, w1);

        // partials: s0 rgb=(c01.x,c01.y,c23.x), s1 rgb=(c23.y,c45.x,c45.y)
        float r   = w0 * c01[k].x + w1 * c23[k].y;
        float g   = w0 * c01[k].y + w1 * c45[k].x;
        float b   = w0 * c23[k].x + w1 * c45[k].y;
        float dep = w0 * z.x      + w1 * z.y;
        float op  = w0 + w1;

        crs[k] = wave_sum(r);
        cgs[k] = wave_sum(g);
        cbs[k] = wave_sum(b);
        dps[k] = wave_sum(dep);
        ops[k] = wave_sum(op);
    }

    if (lane == 0) {
        const int wb = *wb_flag;
        float ad[4];
        #pragma unroll
        for (int k = 0; k < 4; ++k) ad[k] = wb ? (1.0f - ops[k]) : 0.0f;

        // comp_rgb: 12 consecutive floats at out[12*wid]
        float4* co = reinterpret_cast<float4*>(out + (size_t)wid * 12);
        co[0] = make_float4(crs[0] + ad[0], cgs[0] + ad[0], cbs[0] + ad[0], crs[1] + ad[1]);
        co[1] = make_float4(cgs[1] + ad[1], cbs[1] + ad[1], crs[2] + ad[2], cgs[2] + ad[2]);
        co[2] = make_float4(cbs[2] + ad[2], crs[3] + ad[3], cgs[3] + ad[3], cbs[3] + ad[3]);

        reinterpret_cast<float4*>(out + (size_t)N_RAY * 3)[wid] =
            make_float4(dps[0], dps[1], dps[2], dps[3]);
        reinterpret_cast<float4*>(out + (size_t)N_RAY * 4)[wid] =
            make_float4(ops[0], ops[1], ops[2], ops[3]);
    }
}

extern "C" void kernel_launch(void* const* d_in, const int* in_sizes, int n_in,
                              void* d_out, int out_size, void* d_ws, size_t ws_size,
                              hipStream_t stream) {
    const float* rgb    = (const float*)d_in[0];
    const float* sigma  = (const float*)d_in[1];
    const float* z_vals = (const float*)d_in[2];
    const int*   wb     = (const int*)d_in[3];
    float* out = (float*)d_out;

    // 4 waves/block, 4 rays/wave -> 16 rays/block
    const int blocks = N_RAY / 16;   // 8192
    volrender_kernel<<<blocks, 256, 0, stream>>>(rgb, sigma, z_vals, wb, out);
}

// Round 7
// 75.321 us; speedup vs baseline: 1.0648x; 1.0648x over previous
//
#include <hip/hip_runtime.h>

#define N_RAY 131072
#define NS 128
#define BIG_DELTA 1e10f
#define EPS 1e-10f

// DPP move with explicit identity for invalid/masked lanes (bound_ctrl=false).
// Semantics verified on-HW in R6 (passed): row_shr:N = lane i reads lane i-N,
// wave_shr:1 = lane i reads lane i-1 (lane0 -> OLD), wave_shl:1 = lane i reads
// lane i+1 (lane63 -> OLD), row_bcast:15/31 per LLVM atomic-optimizer scan.
#define DPPF(OLD, V, CTRL, RM) \
  __int_as_float(__builtin_amdgcn_update_dpp(__float_as_int(OLD), __float_as_int(V), (CTRL), (RM), 0xf, false))

// Inclusive multiply-scan over 64 lanes (identity = 1.0). 6 DPP ops.
__device__ __forceinline__ float mul_scan_incl(float p) {
    p *= DPPF(1.0f, p, 0x111, 0xf);   // row_shr:1
    p *= DPPF(1.0f, p, 0x112, 0xf);   // row_shr:2
    p *= DPPF(1.0f, p, 0x114, 0xf);   // row_shr:4
    p *= DPPF(1.0f, p, 0x118, 0xf);   // row_shr:8
    p *= DPPF(1.0f, p, 0x142, 0xa);   // row_bcast:15 -> rows 1,3
    p *= DPPF(1.0f, p, 0x143, 0xc);   // row_bcast:31 -> rows 2,3
    return p;
}

// Wave sum; total lands in lane 63. 6 DPP ops.
__device__ __forceinline__ float wave_sum63(float v) {
    v += DPPF(0.0f, v, 0x111, 0xf);
    v += DPPF(0.0f, v, 0x112, 0xf);
    v += DPPF(0.0f, v, 0x114, 0xf);
    v += DPPF(0.0f, v, 0x118, 0xf);
    v += DPPF(0.0f, v, 0x142, 0xa);
    v += DPPF(0.0f, v, 0x143, 0xc);
    return v;
}

// One wave per ray, 2 consecutive samples per lane (float2 coalesced loads).
// All cross-lane traffic via DPP (VALU pipe) - zero LDS/bpermute ops.
__global__ __launch_bounds__(256) void volrender_kernel(
    const float* __restrict__ rgb,
    const float* __restrict__ sigma,
    const float* __restrict__ z_vals,
    const int* __restrict__ wb_flag,
    float* __restrict__ out)
{
    const int tid  = blockIdx.x * blockDim.x + threadIdx.x;
    const int ray  = tid >> 6;
    const int lane = tid & 63;

    const size_t base = (size_t)ray * NS + 2 * lane;

    // ---- issue all loads up front (5 x dwordx2, fully coalesced)
    const float2 z  = *reinterpret_cast<const float2*>(&z_vals[base]);
    const float2 sg = *reinterpret_cast<const float2*>(&sigma[base]);
    const float* rp = rgb + (size_t)ray * (NS * 3) + 6 * lane;
    const float2 c01 = *reinterpret_cast<const float2*>(rp);
    const float2 c23 = *reinterpret_cast<const float2*>(rp + 2);
    const float2 c45 = *reinterpret_cast<const float2*>(rp + 4);

    // deltas: z[2l+2] comes from lane l+1 (wave_shl:1); lane 63 -> BIG_DELTA
    float znext = DPPF(0.0f, z.x, 0x130, 0xf);
    float d0 = z.y - z.x;
    float d1 = (lane == 63) ? BIG_DELTA : (znext - z.y);

    // alpha = 1 - exp(-delta * relu(sigma)); t = 1 - alpha + EPS = e + EPS
    float e0 = __expf(-d0 * fmaxf(sg.x, 0.0f));
    float e1 = __expf(-d1 * fmaxf(sg.y, 0.0f));
    float a0 = 1.0f - e0, a1 = 1.0f - e1;
    float t0 = e0 + EPS,  t1 = e1 + EPS;

    // exclusive cumprod across the wave
    float p = mul_scan_incl(t0 * t1);
    float E = DPPF(1.0f, p, 0x138, 0xf);   // wave_shr:1; lane0 = 1.0

    float w0 = a0 * E;
    float w1 = a1 * (E * t0);

    // weights output: after comp_rgb(3N) + depth(N) + opacity(N)
    float* wout = out + (size_t)N_RAY * 5;
    *reinterpret_cast<float2*>(&wout[base]) = make_float2(w0, w1);

    // partials: s0 rgb=(c01.x,c01.y,c23.x), s1 rgb=(c23.y,c45.x,c45.y)
    float r   = w0 * c01.x + w1 * c23.y;
    float g   = w0 * c01.y + w1 * c45.x;
    float b   = w0 * c23.x + w1 * c45.y;
    float dep = w0 * z.x   + w1 * z.y;

    r   = wave_sum63(r);
    g   = wave_sum63(g);
    b   = wave_sum63(b);
    dep = wave_sum63(dep);

    if (lane == 63) {
        // opacity = sum(w) = 1 - prod(t) + EPS*sum(E) ; EPS term <= 1.3e-8,
        // far below the 0.1 threshold -> take it from the scan total (free).
        float op = 1.0f - p;
        const float add = (*wb_flag) ? (1.0f - op) : 0.0f;
        out[(size_t)ray * 3 + 0] = r + add;
        out[(size_t)ray * 3 + 1] = g + add;
        out[(size_t)ray * 3 + 2] = b + add;
        out[(size_t)N_RAY * 3 + ray] = dep;
        out[(size_t)N_RAY * 4 + ray] = op;
    }
}

extern "C" void kernel_launch(void* const* d_in, const int* in_sizes, int n_in,
                              void* d_out, int out_size, void* d_ws, size_t ws_size,
                              hipStream_t stream) {
    const float* rgb    = (const float*)d_in[0];
    const float* sigma  = (const float*)d_in[1];
    const float* z_vals = (const float*)d_in[2];
    const int*   wb     = (const int*)d_in[3];
    float* out = (float*)d_out;

    // 4 rays per 256-thread block (1 wave per ray)
    const int blocks = N_RAY / 4;   // 32768
    volrender_kernel<<<blocks, 256, 0, stream>>>(rgb, sigma, z_vals, wb, out);
}